// Round 8
// baseline (196.572 us; speedup 1.0000x reference)
//
#include <hip/hip_runtime.h>
#include <stdint.h>
#include <stddef.h>

#define DIM 256
#define NB 16
#define HH 56
#define WW 56
#define HWP (HH*WW)          // 3136
#define PH 62
#define PW 62
#define NPIX (NB*HWP)        // 50176
#define EPSV 1e-5f

using f32x4  = __attribute__((ext_vector_type(4))) float;
using bf16x8 = __attribute__((ext_vector_type(8))) __bf16;

static __device__ __forceinline__ unsigned short f2bf(float f) {
    union { float f; unsigned u; } v; v.f = f;
    unsigned r = v.u + 0x7FFFu + ((v.u >> 16) & 1u);
    return (unsigned short)(r >> 16);
}
static __device__ __forceinline__ float bf2f(unsigned short u) {
    union { unsigned u; float f; } v; v.u = ((unsigned)u) << 16; return v.f;
}
static __device__ __forceinline__ float silu_f(float z) {
    return z / (1.f + __expf(-z));
}

// ---------------- P1: fold BN into weights, merge 1x1 into 3x3 center, merge depthwise ----
__global__ void prep_weights(
    const float* __restrict__ w3, const float* __restrict__ g1, const float* __restrict__ b1,
    const float* __restrict__ m1, const float* __restrict__ v1, const float* __restrict__ w1,
    const float* __restrict__ g2, const float* __restrict__ b2, const float* __restrict__ m2,
    const float* __restrict__ v2, const float* __restrict__ dw7, const float* __restrict__ dwk,
    const float* __restrict__ g3, const float* __restrict__ b3, const float* __restrict__ m3,
    const float* __restrict__ v3,
    unsigned short* __restrict__ WkT, float* __restrict__ dwm, float* __restrict__ biasm,
    float* __restrict__ sc3, float* __restrict__ bi3)
{
    int co = blockIdx.x, t = threadIdx.x;          // t = ci
    float s1 = g1[co] * rsqrtf(v1[co] + EPSV);
    float s2 = g2[co] * rsqrtf(v2[co] + EPSV);
    float w1v = w1[co*DIM + t] * s2;
    const float* w3r = w3 + (size_t)(co*DIM + t)*9;
#pragma unroll
    for (int s = 0; s < 9; ++s) {
        float v = w3r[s]*s1 + (s == 4 ? w1v : 0.f);
        WkT[((size_t)s*DIM + co)*DIM + t] = f2bf(v);   // layout [tap][co][ci]
    }
    if (t < 49) dwm[co*49 + t] = dw7[co*49 + t] + dwk[co*49 + t];
    if (t == 0) {
        biasm[co] = (b1[co] - m1[co]*s1) + (b2[co] - m2[co]*s2);
        float s3 = g3[co] * rsqrtf(v3[co] + EPSV);
        sc3[co] = s3;
        bi3[co] = b3[co] - m3[co]*s3;
    }
}

// ---------------- P2: x NCHW f32 -> padded NHWC bf16 (writes its own halo zeros) --------
__global__ void prep_xpad(const float* __restrict__ x, unsigned short* __restrict__ xpad)
{
    __shared__ float lds[64][57];
    int cc = blockIdx.x;      // 0..3 channel chunk of 64
    int ph = blockIdx.y;      // 0..61 padded row
    int b  = blockIdx.z;      // 0..15
    int t  = threadIdx.x;
    int c0 = cc*64;
    char* rowc = (char*)xpad + ((size_t)(b*PH + ph)*PW)*(DIM*2) + c0*2;

    if (ph < 3 || ph >= HH + 3) {
        uint4 z = {0u,0u,0u,0u};
#pragma unroll
        for (int j = 0; j < 2; ++j) {
            int idx = j*256 + t;
            if (idx < 496) {
                int pix = idx >> 3, q = idx & 7;
                *(uint4*)(rowc + (size_t)pix*(DIM*2) + q*16) = z;
            }
        }
        return;
    }
    if (t < 48) {
        int p = t >> 3, q = t & 7;
        int pw = (p < 3) ? p : (PW - 6 + p);       // 0,1,2, 59,60,61
        uint4 z = {0u,0u,0u,0u};
        *(uint4*)(rowc + (size_t)pw*(DIM*2) + q*16) = z;
    }
    int h = ph - 3;
#pragma unroll
    for (int j = 0; j < 14; ++j) {                   // 64*56 = 3584 = 14*256
        int idx = j*256 + t;
        int c = idx / 56, w = idx % 56;
        lds[c][w] = x[((size_t)(b*DIM + c0 + c)*HH + h)*WW + w];
    }
    __syncthreads();
#pragma unroll
    for (int j = 0; j < 7; ++j) {                    // 56*32 pairs = 1792 = 7*256
        int idx = j*256 + t;
        int w = idx >> 5, cp = idx & 31;
        unsigned lo = f2bf(lds[2*cp][w]);
        unsigned hi = f2bf(lds[2*cp+1][w]);
        unsigned val = lo | (hi << 16);
        *(unsigned*)(rowc + (size_t)(w + 3)*(DIM*2) + 4*cp) = val;
    }
}

// ---------------- P3: merged depthwise 7x7, vectorized LDS reads, 8-wide strips --------
__global__ void depthwise7(const float* __restrict__ x, const float* __restrict__ dwm,
                           unsigned short* __restrict__ dwout)
{
    __shared__ float plane[PH][64];                  // rows padded to 64 (16B-aligned vec reads)
    int c = blockIdx.x, b = blockIdx.y, t = threadIdx.x;
#pragma unroll
    for (int j = 0; j < 4; ++j) {
        int idx = j*256 + t;
        if (idx < 992) ((f32x4*)plane)[idx] = (f32x4){0.f,0.f,0.f,0.f};
    }
    __syncthreads();
    const float* xp = x + ((size_t)b*DIM + c)*HWP;
#pragma unroll
    for (int j = 0; j < 13; ++j) {
        int idx = j*256 + t;
        if (idx < HWP) {
            int h = idx / 56, w = idx % 56;
            plane[h + 3][w + 3] = xp[idx];
        }
    }
    float wr[49];
#pragma unroll
    for (int i = 0; i < 49; ++i) wr[i] = dwm[c*49 + i];   // uniform -> SGPR
    __syncthreads();
    unsigned short* op = dwout + ((size_t)b*DIM + c)*HWP;
#pragma unroll
    for (int j = 0; j < 2; ++j) {                    // 392 octs = 56 rows x 7
        int q = j*256 + t;
        if (q < 392) {
            int h = q / 7, w0 = (q % 7)*8;
            float a[8] = {0.f,0.f,0.f,0.f,0.f,0.f,0.f,0.f};
#pragma unroll
            for (int dy = 0; dy < 7; ++dy) {
                const float* row = &plane[h + dy][w0];
                union { f32x4 v[4]; float s[16]; } rr;
                rr.v[0] = *(const f32x4*)(row);
                rr.v[1] = *(const f32x4*)(row + 4);
                rr.v[2] = *(const f32x4*)(row + 8);
                rr.v[3] = *(const f32x4*)(row + 12);
#pragma unroll
                for (int dx = 0; dx < 7; ++dx) {
                    float wv = wr[dy*7 + dx];
#pragma unroll
                    for (int o = 0; o < 8; ++o) a[o] += rr.s[dx + o] * wv;
                }
            }
            uint4 pk;
            pk.x = (unsigned)f2bf(a[0]) | ((unsigned)f2bf(a[1]) << 16);
            pk.y = (unsigned)f2bf(a[2]) | ((unsigned)f2bf(a[3]) << 16);
            pk.z = (unsigned)f2bf(a[4]) | ((unsigned)f2bf(a[5]) << 16);
            pk.w = (unsigned)f2bf(a[6]) | ((unsigned)f2bf(a[7]) << 16);
            *(uint4*)&op[h*WW + w0] = pk;
        }
    }
}

// ---------------- Main: implicit-GEMM conv3x3, 256x256 tile, m201-stagger pipeline -----
// 8 waves; per-wave output 128(px) x 64(co) => LDS bytes/MFMA halved vs 128^2 (62% ceiling).
// 4 phases/K-tile = (kk,j) quadrants, 16 MFMA each. One half-tile staged per phase:
// B(n+1)->other slot @ph0/ph1 (barrier-safe), A(n+2)->own slot @ph2/ph3 (A-reads done).
// ONE vmcnt(4) per K-tile at ph3 => every half gets >=2 phases of flight; never drain 0.
// All 32 accumulators + frags are NAMED SSA; epilogue fully static (no alloca - rule #20).
__global__ __launch_bounds__(512, 2)
void main_conv(const unsigned short* __restrict__ xpad, const unsigned short* __restrict__ WkT,
               const unsigned short* __restrict__ dwo, const float* __restrict__ biasm,
               const float* __restrict__ sc3, const float* __restrict__ bi3,
               float* __restrict__ out)
{
    __shared__ __align__(16) char smem[131072];      // slot{0,1}: Ah0|Ah1|Bh0|Bh1, 16K each
    int t = threadIdx.x;
    int lane = t & 63, wv = t >> 6;                  // 8 waves
    int wm = wv >> 2, wn = wv & 3;                   // wm: px half (128), wn: co quarter (64)
    int qm = lane & 15, qg = lane >> 4;
    int bx = blockIdx.x;

    int swz = (((t & 7) ^ ((t >> 3) & 7)) << 4);     // pre-swizzled source chunk

    uintptr_t gA4[2][2], gB2[2];
#pragma unroll
    for (int l = 0; l < 2; ++l) {
#pragma unroll
        for (int h = 0; h < 2; ++h) {
            int P = bx*256 + h*128 + l*64 + (t >> 3);
            int bb = P / HWP, rem = P % HWP;
            int hh = rem / WW, ww = rem % WW;
            gA4[l][h] = (uintptr_t)xpad + ((size_t)((bb*PH + hh + 2)*PW + (ww + 2))*DIM)*2 + swz;
        }
        gB2[l] = (uintptr_t)WkT + ((size_t)(l*64 + (t >> 3))*DIM)*2 + swz;
    }

    // 32 named accumulators ACC(j, fi, fc): j = co 32-half, fi = px frag (8), fc = co frag (2)
#define ACC(j,fi,fc) acc_##j##_##fi##_##fc
#define DECLJ(j) f32x4 ACC(j,0,0)={}, ACC(j,0,1)={}, ACC(j,1,0)={}, ACC(j,1,1)={}, \
                       ACC(j,2,0)={}, ACC(j,2,1)={}, ACC(j,3,0)={}, ACC(j,3,1)={}, \
                       ACC(j,4,0)={}, ACC(j,4,1)={}, ACC(j,5,0)={}, ACC(j,5,1)={}, \
                       ACC(j,6,0)={}, ACC(j,6,1)={}, ACC(j,7,0)={}, ACC(j,7,1)={};
    DECLJ(0) DECLJ(1)

    bf16x8 a0,a1,a2,a3,a4,a5,a6,a7, b0,b1;

    auto offsA = [&](int kt) { int s9 = kt >> 2, ch = kt & 3, ky = s9/3, kx = s9 - 3*ky;
                               return (ky*PW + kx)*(DIM*2) + ch*128; };
    auto offsB = [&](int kt) { int s9 = kt >> 2, ch = kt & 3;
                               return s9*(DIM*DIM*2) + ch*128; };

    auto STA = [&](int slot, int h, int offA) {
#pragma unroll
        for (int l = 0; l < 2; ++l)
            __builtin_amdgcn_global_load_lds(
                (const __attribute__((address_space(1))) void*)(gA4[l][h] + offA),
                (__attribute__((address_space(3))) void*)(smem + slot*65536 + h*16384
                    + (l*64 + (t >> 3))*128 + (t & 7)*16),
                16, 0, 0);
    };
    auto STB = [&](int slot, int h, int offB) {
#pragma unroll
        for (int l = 0; l < 2; ++l)
            __builtin_amdgcn_global_load_lds(
                (const __attribute__((address_space(1))) void*)(gB2[l] + offB + h*65536),
                (__attribute__((address_space(3))) void*)(smem + slot*65536 + 32768 + h*16384
                    + (l*64 + (t >> 3))*128 + (t & 7)*16),
                16, 0, 0);
    };

    // LDA(slot, kk): wave's 8 px-frags (rows wm*128 + fi*16 + qm), a0..a7
#define LDA_(slot, kk) { \
    const char* _ba = smem + (slot)*65536 + wm*16384 + qm*128 \
        + (((kk)*64 + qg*16) ^ ((qm & 7) << 4)); \
    a0 = *(const bf16x8*)(_ba);          a1 = *(const bf16x8*)(_ba + 2048); \
    a2 = *(const bf16x8*)(_ba + 4096);   a3 = *(const bf16x8*)(_ba + 6144); \
    a4 = *(const bf16x8*)(_ba + 8192);   a5 = *(const bf16x8*)(_ba + 10240); \
    a6 = *(const bf16x8*)(_ba + 12288);  a7 = *(const bf16x8*)(_ba + 14336); }
    // LDB(slot, j, kk): wave's 2 co-frags at co = wn*64 + j*32 (+fc*16), b0,b1
#define LDB_(slot, j, kk) { \
    const char* _bb = smem + (slot)*65536 + 32768 + (wn >> 1)*16384 \
        + (((wn & 1)*64 + (j)*32 + qm))*128 \
        + (((kk)*64 + qg*16) ^ ((qm & 7) << 4)); \
    b0 = *(const bf16x8*)(_bb);  b1 = *(const bf16x8*)(_bb + 2048); }

#define MFMA_ __builtin_amdgcn_mfma_f32_16x16x32_bf16
#define MMJ(j) { __builtin_amdgcn_s_setprio(1); \
    ACC(j,0,0)=MFMA_(a0,b0,ACC(j,0,0),0,0,0); ACC(j,1,0)=MFMA_(a1,b0,ACC(j,1,0),0,0,0); \
    ACC(j,2,0)=MFMA_(a2,b0,ACC(j,2,0),0,0,0); ACC(j,3,0)=MFMA_(a3,b0,ACC(j,3,0),0,0,0); \
    ACC(j,4,0)=MFMA_(a4,b0,ACC(j,4,0),0,0,0); ACC(j,5,0)=MFMA_(a5,b0,ACC(j,5,0),0,0,0); \
    ACC(j,6,0)=MFMA_(a6,b0,ACC(j,6,0),0,0,0); ACC(j,7,0)=MFMA_(a7,b0,ACC(j,7,0),0,0,0); \
    ACC(j,0,1)=MFMA_(a0,b1,ACC(j,0,1),0,0,0); ACC(j,1,1)=MFMA_(a1,b1,ACC(j,1,1),0,0,0); \
    ACC(j,2,1)=MFMA_(a2,b1,ACC(j,2,1),0,0,0); ACC(j,3,1)=MFMA_(a3,b1,ACC(j,3,1),0,0,0); \
    ACC(j,4,1)=MFMA_(a4,b1,ACC(j,4,1),0,0,0); ACC(j,5,1)=MFMA_(a5,b1,ACC(j,5,1),0,0,0); \
    ACC(j,6,1)=MFMA_(a6,b1,ACC(j,6,1),0,0,0); ACC(j,7,1)=MFMA_(a7,b1,ACC(j,7,1),0,0,0); \
    __builtin_amdgcn_s_setprio(0); }

#define VMW4() asm volatile("s_waitcnt vmcnt(4)" ::: "memory")
#define VMW0() asm volatile("s_waitcnt vmcnt(0)" ::: "memory")
#define BARX() { __builtin_amdgcn_sched_barrier(0); __builtin_amdgcn_s_barrier(); \
                 __builtin_amdgcn_sched_barrier(0); }

    // K-tile n in slot s: stage B(n+1)->s^1 @ph0/ph1, A(n+2)->s @ph2/ph3, vmcnt(4) @ph3.
#define KTILE(s, oB1, oA2) { \
    LDA_(s,0); LDB_(s,0,0); STB((s)^1, 0, oB1); BARX(); MMJ(0); BARX(); \
    LDB_(s,1,0);            STB((s)^1, 1, oB1); BARX(); MMJ(1); BARX(); \
    LDA_(s,1); LDB_(s,0,1); STA(s, 0, oA2);     BARX(); MMJ(0); BARX(); \
    LDB_(s,1,1);            STA(s, 1, oA2);     BARX(); MMJ(1); VMW4(); BARX(); }

    // prologue: A(0),B(0) -> slot0; A(1) -> slot1
    { int oA0 = offsA(0), oB0 = offsB(0), oA1 = offsA(1);
      STA(0,0,oA0); STA(0,1,oA0); STB(0,0,oB0); STB(0,1,oB0); STA(1,0,oA1); STA(1,1,oA1); }
    VMW4(); BARX();

#pragma unroll 1
    for (int i = 0; i < 17; ++i) {           // kt 0..33; stages B(1..34), A(2..35)
        KTILE(0, offsB(2*i + 1), offsA(2*i + 2));
        KTILE(1, offsB(2*i + 2), offsA(2*i + 3));
    }
    // kt34 (slot0): stage B(35) only; drain at end
    { int oB35 = offsB(35);
      LDA_(0,0); LDB_(0,0,0); STB(1, 0, oB35); BARX(); MMJ(0); BARX();
      LDB_(0,1,0);            STB(1, 1, oB35); BARX(); MMJ(1); BARX();
      LDA_(0,1); LDB_(0,0,1);                  BARX(); MMJ(0); BARX();
      LDB_(0,1,1);                             BARX(); MMJ(1); VMW0(); BARX(); }
    // kt35 (slot1): no stages, no barriers needed
    LDA_(1,0); LDB_(1,0,0); MMJ(0);
    LDB_(1,1,0);            MMJ(1);
    LDA_(1,1); LDB_(1,0,1); MMJ(0);
    LDB_(1,1,1);            MMJ(1);

#undef KTILE
#undef VMW4
#undef VMW0

    // ---- epilogue: fully static; per-wave disjoint LDS region (slot0 area, safe) ----
    float* ep = (float*)smem + wv*1088;               // 64 co-slots x 16 px, stride 17
#define EPI(fi) { \
    _Pragma("unroll") \
    for (int r = 0; r < 4; ++r) { \
        ep[( 0 + qm)*17 + 4*qg + r] = ACC(0,fi,0)[r]; \
        ep[(16 + qm)*17 + 4*qg + r] = ACC(0,fi,1)[r]; \
        ep[(32 + qm)*17 + 4*qg + r] = ACC(1,fi,0)[r]; \
        ep[(48 + qm)*17 + 4*qg + r] = ACC(1,fi,1)[r]; \
    } \
    int P = bx*256 + wm*128 + fi*16 + qm; \
    int bb = P / HWP, rem = P % HWP; \
    size_t obase = (size_t)bb*DIM*HWP + rem; \
    _Pragma("unroll") \
    for (int j2 = 0; j2 < 16; ++j2) { \
        int col = j2*4 + qg; \
        int cog = wn*64 + col; \
        float z = ep[col*17 + qm] + biasm[cog]; \
        float rep = silu_f(z); \
        float y = rep + bf2f(dwo[obase + (size_t)cog*HWP]); \
        float yy = y * sc3[cog] + bi3[cog]; \
        out[obase + (size_t)cog*HWP] = silu_f(yy); \
    } }

    EPI(0) EPI(1) EPI(2) EPI(3) EPI(4) EPI(5) EPI(6) EPI(7)
#undef EPI
#undef MMJ
#undef MFMA_
#undef LDA_
#undef LDB_
#undef BARX
#undef ACC
#undef DECLJ
}

// ---------------- launch ----------------
extern "C" void kernel_launch(void* const* d_in, const int* in_sizes, int n_in,
                              void* d_out, int out_size, void* d_ws, size_t ws_size,
                              hipStream_t stream)
{
    (void)in_sizes; (void)n_in; (void)out_size; (void)ws_size;
    const float* x   = (const float*)d_in[0];
    const float* w3  = (const float*)d_in[1];
    const float* g1  = (const float*)d_in[2];
    const float* b1  = (const float*)d_in[3];
    const float* m1  = (const float*)d_in[4];
    const float* v1  = (const float*)d_in[5];
    const float* w1  = (const float*)d_in[6];
    const float* g2  = (const float*)d_in[7];
    const float* b2  = (const float*)d_in[8];
    const float* m2  = (const float*)d_in[9];
    const float* v2  = (const float*)d_in[10];
    const float* dw7 = (const float*)d_in[11];
    const float* dwk = (const float*)d_in[12];
    const float* g3  = (const float*)d_in[13];
    const float* b3  = (const float*)d_in[14];
    const float* m3  = (const float*)d_in[15];
    const float* v3  = (const float*)d_in[16];
    float* out = (float*)d_out;

    char* ws = (char*)d_ws;
    unsigned short* xpad = (unsigned short*)(ws);                 // 16*62*62*256*2 = 31,490,048
    unsigned short* WkT  = (unsigned short*)(ws + 31490048);      // 9*256*256*2    =  1,179,648
    unsigned short* dwo  = (unsigned short*)(ws + 32669696);      // 16*256*3136*2  = 25,690,112
    float* dwm   = (float*)(ws + 58359808);                       // 256*49*4
    float* biasm = (float*)(ws + 58409984);
    float* sc3   = (float*)(ws + 58411008);
    float* bi3   = (float*)(ws + 58412032);                       // end ~58.4 MB

    prep_weights<<<dim3(DIM), dim3(256), 0, stream>>>(
        w3, g1, b1, m1, v1, w1, g2, b2, m2, v2, dw7, dwk, g3, b3, m3, v3,
        WkT, dwm, biasm, sc3, bi3);
    prep_xpad<<<dim3(4, PH, NB), dim3(256), 0, stream>>>(x, xpad);
    depthwise7<<<dim3(DIM, NB), dim3(256), 0, stream>>>(x, dwm, dwo);
    main_conv<<<dim3(NPIX/256), dim3(512), 0, stream>>>(xpad, WkT, dwo, biasm, sc3, bi3, out);
}

// Round 9
// 166.149 us; speedup vs baseline: 1.1831x; 1.1831x over previous
//
#include <hip/hip_runtime.h>
#include <stdint.h>
#include <stddef.h>

#define DIM 256
#define NB 16
#define HH 56
#define WW 56
#define HWP (HH*WW)          // 3136
#define PH 62
#define PW 62
#define NPIX (NB*HWP)        // 50176
#define EPSV 1e-5f

using f32x4  = __attribute__((ext_vector_type(4))) float;
using f32x16 = __attribute__((ext_vector_type(16))) float;
using bf16x8 = __attribute__((ext_vector_type(8))) __bf16;

static __device__ __forceinline__ unsigned short f2bf(float f) {
    union { float f; unsigned u; } v; v.f = f;
    unsigned r = v.u + 0x7FFFu + ((v.u >> 16) & 1u);
    return (unsigned short)(r >> 16);
}
static __device__ __forceinline__ float bf2f(unsigned short u) {
    union { unsigned u; float f; } v; v.u = ((unsigned)u) << 16; return v.f;
}
static __device__ __forceinline__ float silu_f(float z) {
    return z / (1.f + __expf(-z));
}

// ---------------- P1: fold BN into weights, merge 1x1 into 3x3 center, merge depthwise ----
__global__ void prep_weights(
    const float* __restrict__ w3, const float* __restrict__ g1, const float* __restrict__ b1,
    const float* __restrict__ m1, const float* __restrict__ v1, const float* __restrict__ w1,
    const float* __restrict__ g2, const float* __restrict__ b2, const float* __restrict__ m2,
    const float* __restrict__ v2, const float* __restrict__ dw7, const float* __restrict__ dwk,
    const float* __restrict__ g3, const float* __restrict__ b3, const float* __restrict__ m3,
    const float* __restrict__ v3,
    unsigned short* __restrict__ WkT, float* __restrict__ dwm, float* __restrict__ biasm,
    float* __restrict__ sc3, float* __restrict__ bi3)
{
    int co = blockIdx.x, t = threadIdx.x;          // t = ci
    float s1 = g1[co] * rsqrtf(v1[co] + EPSV);
    float s2 = g2[co] * rsqrtf(v2[co] + EPSV);
    float w1v = w1[co*DIM + t] * s2;
    const float* w3r = w3 + (size_t)(co*DIM + t)*9;
#pragma unroll
    for (int s = 0; s < 9; ++s) {
        float v = w3r[s]*s1 + (s == 4 ? w1v : 0.f);
        WkT[((size_t)s*DIM + co)*DIM + t] = f2bf(v);   // layout [tap][co][ci]
    }
    if (t < 49) dwm[co*49 + t] = dw7[co*49 + t] + dwk[co*49 + t];
    if (t == 0) {
        biasm[co] = (b1[co] - m1[co]*s1) + (b2[co] - m2[co]*s2);
        float s3 = g3[co] * rsqrtf(v3[co] + EPSV);
        sc3[co] = s3;
        bi3[co] = b3[co] - m3[co]*s3;
    }
}

// ---------------- P2: x NCHW f32 -> padded NHWC bf16 (writes its own halo zeros) --------
__global__ void prep_xpad(const float* __restrict__ x, unsigned short* __restrict__ xpad)
{
    __shared__ float lds[64][57];
    int cc = blockIdx.x;      // 0..3 channel chunk of 64
    int ph = blockIdx.y;      // 0..61 padded row
    int b  = blockIdx.z;      // 0..15
    int t  = threadIdx.x;
    int c0 = cc*64;
    char* rowc = (char*)xpad + ((size_t)(b*PH + ph)*PW)*(DIM*2) + c0*2;

    if (ph < 3 || ph >= HH + 3) {
        uint4 z = {0u,0u,0u,0u};
#pragma unroll
        for (int j = 0; j < 2; ++j) {
            int idx = j*256 + t;
            if (idx < 496) {
                int pix = idx >> 3, q = idx & 7;
                *(uint4*)(rowc + (size_t)pix*(DIM*2) + q*16) = z;
            }
        }
        return;
    }
    if (t < 48) {
        int p = t >> 3, q = t & 7;
        int pw = (p < 3) ? p : (PW - 6 + p);       // 0,1,2, 59,60,61
        uint4 z = {0u,0u,0u,0u};
        *(uint4*)(rowc + (size_t)pw*(DIM*2) + q*16) = z;
    }
    int h = ph - 3;
#pragma unroll
    for (int j = 0; j < 14; ++j) {                   // 64*56 = 3584 = 14*256
        int idx = j*256 + t;
        int c = idx / 56, w = idx % 56;
        lds[c][w] = x[((size_t)(b*DIM + c0 + c)*HH + h)*WW + w];
    }
    __syncthreads();
#pragma unroll
    for (int j = 0; j < 7; ++j) {                    // 56*32 pairs = 1792 = 7*256
        int idx = j*256 + t;
        int w = idx >> 5, cp = idx & 31;
        unsigned lo = f2bf(lds[2*cp][w]);
        unsigned hi = f2bf(lds[2*cp+1][w]);
        unsigned val = lo | (hi << 16);
        *(unsigned*)(rowc + (size_t)(w + 3)*(DIM*2) + 4*cp) = val;
    }
}

// ---------------- P3: merged depthwise 7x7, vectorized LDS reads, 8-wide strips --------
__global__ void depthwise7(const float* __restrict__ x, const float* __restrict__ dwm,
                           unsigned short* __restrict__ dwout)
{
    __shared__ float plane[PH][64];                  // rows padded to 64 (16B-aligned vec reads)
    int c = blockIdx.x, b = blockIdx.y, t = threadIdx.x;
#pragma unroll
    for (int j = 0; j < 4; ++j) {
        int idx = j*256 + t;
        if (idx < 992) ((f32x4*)plane)[idx] = (f32x4){0.f,0.f,0.f,0.f};
    }
    __syncthreads();
    const float* xp = x + ((size_t)b*DIM + c)*HWP;
#pragma unroll
    for (int j = 0; j < 13; ++j) {
        int idx = j*256 + t;
        if (idx < HWP) {
            int h = idx / 56, w = idx % 56;
            plane[h + 3][w + 3] = xp[idx];
        }
    }
    float wr[49];
#pragma unroll
    for (int i = 0; i < 49; ++i) wr[i] = dwm[c*49 + i];   // uniform -> SGPR
    __syncthreads();
    unsigned short* op = dwout + ((size_t)b*DIM + c)*HWP;
#pragma unroll
    for (int j = 0; j < 2; ++j) {                    // 392 octs = 56 rows x 7
        int q = j*256 + t;
        if (q < 392) {
            int h = q / 7, w0 = (q % 7)*8;
            float a[8] = {0.f,0.f,0.f,0.f,0.f,0.f,0.f,0.f};
#pragma unroll
            for (int dy = 0; dy < 7; ++dy) {
                const float* row = &plane[h + dy][w0];
                union { f32x4 v[4]; float s[16]; } rr;
                rr.v[0] = *(const f32x4*)(row);
                rr.v[1] = *(const f32x4*)(row + 4);
                rr.v[2] = *(const f32x4*)(row + 8);
                rr.v[3] = *(const f32x4*)(row + 12);
#pragma unroll
                for (int dx = 0; dx < 7; ++dx) {
                    float wv = wr[dy*7 + dx];
#pragma unroll
                    for (int o = 0; o < 8; ++o) a[o] += rr.s[dx + o] * wv;
                }
            }
            uint4 pk;
            pk.x = (unsigned)f2bf(a[0]) | ((unsigned)f2bf(a[1]) << 16);
            pk.y = (unsigned)f2bf(a[2]) | ((unsigned)f2bf(a[3]) << 16);
            pk.z = (unsigned)f2bf(a[4]) | ((unsigned)f2bf(a[5]) << 16);
            pk.w = (unsigned)f2bf(a[6]) | ((unsigned)f2bf(a[7]) << 16);
            *(uint4*)&op[h*WW + w0] = pk;
        }
    }
}

// ---------------- Main: implicit-GEMM conv3x3, 128x128 tile, 32x32x16 MFMA -------------
// R2's validated structure (4 waves, 2 blocks/CU, dbuf 2x32KB, XOR-swizzled staging) with
// (a) mfma_f32_32x32x16_bf16: half the MFMA instructions, -17% matrix-pipe cycles, and
//     acc = 4 named f32x16 (no alloca possible - rule #20);
// (b) counted vmcnt(8) + raw barrier (R7-validated loop): next stage's 8 loads stay in
//     flight across the whole compute, never drained to 0 in steady state (T4); setprio (T5).
__global__ __launch_bounds__(256, 2)
void main_conv(const unsigned short* __restrict__ xpad, const unsigned short* __restrict__ WkT,
               const unsigned short* __restrict__ dwo, const float* __restrict__ biasm,
               const float* __restrict__ sc3, const float* __restrict__ bi3,
               float* __restrict__ out)
{
    __shared__ __align__(16) char smem[65536];       // buf{0,1}: A 16K + B 16K
    int t = threadIdx.x;
    int lane = t & 63, wv = t >> 6;
    int wm = wv >> 1, wn = wv & 1;                   // wave quadrant: px-half x co-half
    int r5 = lane & 31, hi = lane >> 5, l7 = lane & 7;
    int bx = blockIdx.x;

    int swz = (((lane & 7) ^ ((lane >> 3) & 7)) << 4);   // pre-swizzled source chunk

    uintptr_t gA[4], gB[4];
#pragma unroll
    for (int r = 0; r < 4; ++r) {
        int pixt = r*32 + wv*8 + (lane >> 3);
        int P = bx*128 + pixt;
        int bb = P / HWP, rem = P % HWP;
        int h = rem / WW, w = rem % WW;
        gA[r] = (uintptr_t)xpad + ((size_t)((bb*PH + h + 2)*PW + (w + 2))*DIM)*2 + swz;
        int cog = blockIdx.y*128 + pixt;
        gB[r] = (uintptr_t)WkT + ((size_t)cog*DIM)*2 + swz;
    }

    // 4 named f32x16 accumulators (32x32 C/D = 16 regs each)
    f32x16 acc00 = {}, acc01 = {}, acc10 = {}, acc11 = {};
    bf16x8 a0, a1, b0, b1;

    auto stage = [&](int s, int buf) {
        int s9 = s >> 2, ch = s & 3;
        int ky = s9 / 3, kx = s9 - ky*3;
        int offA = (ky*PW + kx)*(DIM*2) + ch*128;
        int offB = s9*(DIM*DIM*2) + ch*128;
        char* base = smem + buf*32768;
#pragma unroll
        for (int r = 0; r < 4; ++r) {
            __builtin_amdgcn_global_load_lds(
                (const __attribute__((address_space(1))) void*)(gA[r] + offA),
                (__attribute__((address_space(3))) void*)(base + (r*32 + wv*8)*128),
                16, 0, 0);
            __builtin_amdgcn_global_load_lds(
                (const __attribute__((address_space(1))) void*)(gB[r] + offB),
                (__attribute__((address_space(3))) void*)(base + 16384 + (r*32 + wv*8)*128),
                16, 0, 0);
        }
    };

    // per-lane fragment chunk offsets: logical chunk = ks*2 + hi, phys = logical ^ (row&7),
    // row&7 == lane&7 for our row mapping (row = base32 + (lane&31))
    const int cb0 = (((0 + hi) ^ l7) << 4);
    const int cb1 = (((2 + hi) ^ l7) << 4);
    const int cb2 = (((4 + hi) ^ l7) << 4);
    const int cb3 = (((6 + hi) ^ l7) << 4);
    const int rowb = r5 * 128;

#define MFMA32 __builtin_amdgcn_mfma_f32_32x32x16_bf16
#define KSTEP(pA, pB, cb) { \
    a0 = *(const bf16x8*)((pA) + (cb)); \
    a1 = *(const bf16x8*)((pA) + 4096 + (cb)); \
    b0 = *(const bf16x8*)((pB) + (cb)); \
    b1 = *(const bf16x8*)((pB) + 4096 + (cb)); \
    __builtin_amdgcn_s_setprio(1); \
    acc00 = MFMA32(a0, b0, acc00, 0, 0, 0); \
    acc01 = MFMA32(a0, b1, acc01, 0, 0, 0); \
    acc10 = MFMA32(a1, b0, acc10, 0, 0, 0); \
    acc11 = MFMA32(a1, b1, acc11, 0, 0, 0); \
    __builtin_amdgcn_s_setprio(0); }

    auto compute = [&](int buf) {
        const char* pA = smem + buf*32768 + wm*8192 + rowb;           // A: px rows
        const char* pB = smem + buf*32768 + 16384 + wn*8192 + rowb;   // B: co rows
        KSTEP(pA, pB, cb0)
        KSTEP(pA, pB, cb1)
        KSTEP(pA, pB, cb2)
        KSTEP(pA, pB, cb3)
    };

#define VMW8() asm volatile("s_waitcnt vmcnt(8)" ::: "memory")
#define VMW0() asm volatile("s_waitcnt vmcnt(0)" ::: "memory")
#define BARX() { asm volatile("" ::: "memory"); __builtin_amdgcn_s_barrier(); asm volatile("" ::: "memory"); }

    stage(0, 0);
    stage(1, 1);
    VMW8(); BARX();                       // stage(0) landed & published
#pragma unroll 1
    for (int s = 0; s < 36; ++s) {
        compute(s & 1);                   // stage(s+1) flying underneath
        BARX();                           // all waves done reading buf (s&1)
        if (s <= 33) {
            stage(s + 2, s & 1);          // refill the buffer just freed
            VMW8();                       // stage(s+1) landed (8 newest = stage(s+2))
            BARX();                       // publish
        } else if (s == 34) {
            VMW0();                       // drain stage(35) for the last step
            BARX();
        }
    }
#undef VMW8
#undef VMW0

    BARX();                               // all computes done before smem reuse
#undef BARX

    // ---- epilogue: per-ti transpose through LDS (per-wave disjoint region) ----
    // C/D 32x32 layout: col = lane&31 (co), row = (reg&3) + 8*(reg>>2) + 4*hi (px)
    float* ep = (float*)smem + wv*2112;   // 64 co x 33 px f32 = 8448 B per wave
#define EPI(ti, aT0, aT1) { \
    _Pragma("unroll") \
    for (int rg = 0; rg < 16; ++rg) { \
        int prow = (rg & 3) + 8*(rg >> 2) + 4*hi; \
        ep[r5*33 + prow]        = aT0[rg]; \
        ep[(32 + r5)*33 + prow] = aT1[rg]; \
    } \
    asm volatile("s_waitcnt lgkmcnt(0)" ::: "memory"); \
    __builtin_amdgcn_sched_barrier(0); \
    int P0 = bx*128 + wm*64 + (ti)*32;                 /* wave-uniform, 32 | P0 */ \
    int bb = P0 / HWP, rem = P0 % HWP;                 /* 32-px run stays in-image */ \
    size_t obase = (size_t)bb*DIM*HWP + rem + r5; \
    _Pragma("unroll") \
    for (int j2 = 0; j2 < 32; ++j2) { \
        int cl = j2*2 + hi;                            /* 0..63 co-local */ \
        int cog = blockIdx.y*128 + wn*64 + cl; \
        float z = ep[cl*33 + r5] + biasm[cog]; \
        float rep = silu_f(z); \
        float y = rep + bf2f(dwo[obase + (size_t)cog*HWP]); \
        float yy = y * sc3[cog] + bi3[cog]; \
        out[obase + (size_t)cog*HWP] = silu_f(yy); \
    } \
    asm volatile("s_waitcnt lgkmcnt(0)" ::: "memory"); \
    __builtin_amdgcn_sched_barrier(0); }

    EPI(0, acc00, acc01)
    EPI(1, acc10, acc11)
#undef EPI
#undef KSTEP
#undef MFMA32
}

// ---------------- launch ----------------
extern "C" void kernel_launch(void* const* d_in, const int* in_sizes, int n_in,
                              void* d_out, int out_size, void* d_ws, size_t ws_size,
                              hipStream_t stream)
{
    (void)in_sizes; (void)n_in; (void)out_size; (void)ws_size;
    const float* x   = (const float*)d_in[0];
    const float* w3  = (const float*)d_in[1];
    const float* g1  = (const float*)d_in[2];
    const float* b1  = (const float*)d_in[3];
    const float* m1  = (const float*)d_in[4];
    const float* v1  = (const float*)d_in[5];
    const float* w1  = (const float*)d_in[6];
    const float* g2  = (const float*)d_in[7];
    const float* b2  = (const float*)d_in[8];
    const float* m2  = (const float*)d_in[9];
    const float* v2  = (const float*)d_in[10];
    const float* dw7 = (const float*)d_in[11];
    const float* dwk = (const float*)d_in[12];
    const float* g3  = (const float*)d_in[13];
    const float* b3  = (const float*)d_in[14];
    const float* m3  = (const float*)d_in[15];
    const float* v3  = (const float*)d_in[16];
    float* out = (float*)d_out;

    char* ws = (char*)d_ws;
    unsigned short* xpad = (unsigned short*)(ws);                 // 16*62*62*256*2 = 31,490,048
    unsigned short* WkT  = (unsigned short*)(ws + 31490048);      // 9*256*256*2    =  1,179,648
    unsigned short* dwo  = (unsigned short*)(ws + 32669696);      // 16*256*3136*2  = 25,690,112
    float* dwm   = (float*)(ws + 58359808);                       // 256*49*4
    float* biasm = (float*)(ws + 58409984);
    float* sc3   = (float*)(ws + 58411008);
    float* bi3   = (float*)(ws + 58412032);                       // end ~58.4 MB

    prep_weights<<<dim3(DIM), dim3(256), 0, stream>>>(
        w3, g1, b1, m1, v1, w1, g2, b2, m2, v2, dw7, dwk, g3, b3, m3, v3,
        WkT, dwm, biasm, sc3, bi3);
    prep_xpad<<<dim3(4, PH, NB), dim3(256), 0, stream>>>(x, xpad);
    depthwise7<<<dim3(DIM, NB), dim3(256), 0, stream>>>(x, dwm, dwo);
    main_conv<<<dim3(NPIX/128, 2), dim3(256), 0, stream>>>(xpad, WkT, dwo, biasm, sc3, bi3, out);
}